// Round 12
// baseline (1454.633 us; speedup 1.0000x reference)
//
#include <hip/hip_runtime.h>
#include <math.h>

#define BB 4
#define CC 64
#define HH 256
#define WW 256
#define WF 129
#define NPIX (WF*HH)                 // 33024
#define NS ((size_t)BB*CC*NPIX)      // 8454144 floats per plane-set
#define TWOPI 6.283185307179586f

typedef __attribute__((ext_vector_type(8))) short short8v;
typedef __attribute__((ext_vector_type(4))) float float4v;
typedef __attribute__((ext_vector_type(16))) float float16v;

// ---------------- four-step 256-point complex FFT in LDS ----------------
__device__ __forceinline__ float2 cmulf(float2 a, float2 b) {
    return make_float2(a.x*b.x - a.y*b.y, a.x*b.y + a.y*b.x);
}

template<int SIGN>
__device__ __forceinline__ float2 fft256_lds(const float2* __restrict__ xs,
                                             float2* __restrict__ ys,
                                             const float2* __restrict__ tw,
                                             const float2* __restrict__ tw16,
                                             int t) {
    int k1 = t & 15, n2 = t >> 4;
    float2 acc = make_float2(0.f, 0.f);
    #pragma unroll
    for (int n1 = 0; n1 < 16; ++n1) {
        float2 v = xs[n1*16 + n2];
        float2 w = tw16[(n1*k1) & 15];
        float ws = (SIGN < 0) ? -w.y : w.y;
        acc.x = fmaf(v.x, w.x, fmaf(-v.y, ws, acc.x));
        acc.y = fmaf(v.x, ws, fmaf( v.y, w.x, acc.y));
    }
    float2 w2 = tw[n2*k1];
    float w2s = (SIGN < 0) ? -w2.y : w2.y;
    ys[t] = cmulf(acc, make_float2(w2.x, w2s));
    __syncthreads();
    float2 acc2 = make_float2(0.f, 0.f);
    #pragma unroll
    for (int m2 = 0; m2 < 16; ++m2) {
        float2 v = ys[m2*16 + k1];
        float2 w = tw16[(m2*n2) & 15];
        float ws = (SIGN < 0) ? -w.y : w.y;
        acc2.x = fmaf(v.x, w.x, fmaf(-v.y, ws, acc2.x));
        acc2.y = fmaf(v.x, ws, fmaf( v.y, w.x, acc2.y));
    }
    return acc2;
}

// In-place variant (single buffer, two internal barriers) — identical arithmetic.
template<int SIGN>
__device__ __forceinline__ float2 fft256_ip(float2* __restrict__ buf,
                                            const float2* __restrict__ tw,
                                            const float2* __restrict__ tw16,
                                            int t) {
    int k1 = t & 15, n2 = t >> 4;
    float2 acc = make_float2(0.f, 0.f);
    #pragma unroll
    for (int n1 = 0; n1 < 16; ++n1) {
        float2 v = buf[n1*16 + n2];
        float2 w = tw16[(n1*k1) & 15];
        float ws = (SIGN < 0) ? -w.y : w.y;
        acc.x = fmaf(v.x, w.x, fmaf(-v.y, ws, acc.x));
        acc.y = fmaf(v.x, ws, fmaf( v.y, w.x, acc.y));
    }
    float2 w2 = tw[n2*k1];
    float w2s = (SIGN < 0) ? -w2.y : w2.y;
    float2 mid = cmulf(acc, make_float2(w2.x, w2s));
    __syncthreads();
    buf[t] = mid;
    __syncthreads();
    float2 acc2 = make_float2(0.f, 0.f);
    #pragma unroll
    for (int m2 = 0; m2 < 16; ++m2) {
        float2 v = buf[m2*16 + k1];
        float2 w = tw16[(m2*n2) & 15];
        float ws = (SIGN < 0) ? -w.y : w.y;
        acc2.x = fmaf(v.x, w.x, fmaf(-v.y, ws, acc2.x));
        acc2.y = fmaf(v.x, ws, fmaf( v.y, w.x, acc2.y));
    }
    return acc2;
}

// ------------- K_tw: fill twiddle table + zero page -------------
__global__ void k_tw(float2* __restrict__ twg, float* __restrict__ zp) {
    int m = threadIdx.x;
    float s, c;
    sincosf((TWOPI/256.f) * (float)m, &s, &c);
    twg[m] = make_float2(c, s);
    zp[m] = 0.f;
}

// ---------------- K1: row rfft, 16 rows per block, LDS-tile staged ----------
__global__ __launch_bounds__(256) void k_fft_rows(const float* __restrict__ x,
                                                  const float2* __restrict__ twg,
                                                  float* __restrict__ r1re,
                                                  float* __restrict__ r1im) {
    __shared__ float2 work[256];
    __shared__ float tileRe[16][132], tileIm[16][132];
    __shared__ float2 tw[256];
    __shared__ float2 tw16[16];
    int t = threadIdx.x;
    int bid = blockIdx.x;
    int yt = bid & 15;
    int bc = bid >> 4;
    int y0 = yt*16;
    tw[t] = twg[t];
    if (t < 16) tw16[t] = twg[t*16];
    const float* xb = x + (size_t)bc*HH*WW + (size_t)y0*WW;
    for (int r = 0; r < 16; ++r) {
        __syncthreads();                 // work reusable; tw visible at r=0
        work[t] = make_float2(xb[r*WW + t], 0.f);
        __syncthreads();
        float2 X = fft256_ip<-1>(work, tw, tw16, t);
        if (t < WF) { tileRe[r][t] = X.x; tileIm[r][t] = X.y; }
    }
    __syncthreads();
    if (t < WF) {
        size_t base = ((size_t)bc*WF + t)*HH + y0;
        #pragma unroll
        for (int g = 0; g < 4; ++g) {
            float4 vr = make_float4(tileRe[g*4][t], tileRe[g*4+1][t],
                                    tileRe[g*4+2][t], tileRe[g*4+3][t]);
            float4 vi = make_float4(tileIm[g*4][t], tileIm[g*4+1][t],
                                    tileIm[g*4+2][t], tileIm[g*4+3][t]);
            *(float4*)&r1re[base + g*4] = vr;
            *(float4*)&r1im[base + g*4] = vi;
        }
    }
}

// ------------- K2: column fft + amp/pha -------------
__global__ __launch_bounds__(256) void k_fft_cols(const float* __restrict__ r1re,
                                                  const float* __restrict__ r1im,
                                                  const float2* __restrict__ twg,
                                                  float* __restrict__ amp,
                                                  float* __restrict__ pha) {
    __shared__ float2 xs[256], ys[256];
    __shared__ float2 tw[256];
    __shared__ float2 tw16[16];
    int t = threadIdx.x;
    int bid = blockIdx.x;
    int k = bid % WF;
    int bc = bid / WF;
    size_t base = ((size_t)bc*WF + k)*HH;
    tw[t] = twg[t];
    if (t < 16) tw16[t] = twg[t*16];
    xs[t] = make_float2(r1re[base + t], r1im[base + t]);
    __syncthreads();
    float2 X = fft256_lds<-1>(xs, ys, tw, tw16, t);
    amp[base + t] = sqrtf(X.x*X.x + X.y*X.y);
    pha[base + t] = atan2f(X.y, X.x);
}

// ------------- K_pack: [b,c,k,m] -> channel-innermost [b,k,m,c] -------------
__global__ __launch_bounds__(256) void k_pack(const float* __restrict__ src,
                                              float* __restrict__ dst) {
    __shared__ float tile[64][65];
    int tid = threadIdx.x;
    int bid = blockIdx.x;
    int it = bid & 3;
    int rest = bid >> 2;
    int k = rest % WF;
    int b = rest / WF;
    int i0 = it*64;
    int ii = tid & 63;
    int cg = tid >> 6;
    for (int rep = 0; rep < 16; ++rep) {
        int c = cg*16 + rep;
        tile[c][ii] = src[(size_t)(b*CC + c)*NPIX + (size_t)k*HH + i0 + ii];
    }
    __syncthreads();
    for (int rep = 0; rep < 16; ++rep) {
        int m = cg*16 + rep;
        dst[((size_t)(b*WF + k)*HH + i0 + m)*CC + ii] = tile[ii][m];
    }
}

// ------------- bf16 helpers -------------
__device__ __forceinline__ unsigned short bf16r(float f) {
    unsigned u = __float_as_uint(f);
    unsigned r = (u + 0x7FFFu + ((u >> 16) & 1u)) >> 16;
    return (unsigned short)r;
}
__device__ __forceinline__ float bf16f(unsigned short h) {
    return __uint_as_float(((unsigned)h) << 16);
}

// ------------- K_wct: wc[oc][c][3][3] -> split bf16 [oc][pos*64+c] -------------
__global__ void k_wct(const float* __restrict__ wc,
                      unsigned short* __restrict__ wh,
                      unsigned short* __restrict__ wl) {
    int idx = blockIdx.x*256 + threadIdx.x;   // 64*576 = 36864
    if (idx < 64*576) {
        int k = idx % 576;
        int oc = idx / 576;
        int pos = k >> 6;
        int c = k & 63;
        float v = wc[((size_t)oc*64 + c)*9 + pos];
        unsigned short h = bf16r(v);
        wh[idx] = h;
        wl[idx] = bf16r(v - bf16f(h));
    }
}

// ------------- K_wsplit: w0[oc][c][5][5] -> whT/wlT [tap][oc][c] bf16 split ----
__global__ void k_wsplit(const float* __restrict__ w0,
                         unsigned short* __restrict__ whT,
                         unsigned short* __restrict__ wlT) {
    int idx = blockIdx.x*256 + threadIdx.x;   // 25*64*64 = 102400
    if (idx < 25*64*64) {
        int c = idx & 63;
        int t = idx >> 6;
        int oc = t & 63;
        int tap = t >> 6;
        float v = w0[((size_t)oc*CC + c)*25 + tap];
        unsigned short h = bf16r(v);
        float l = v - bf16f(h);
        whT[idx] = h;
        wlT[idx] = bf16r(l);
    }
}

// ------------- K_wpt: wp[oc][c][3][3] -> wpt[c][oc*9+pos] (both planes) -------
__global__ void k_wpt(const float* __restrict__ wpa, const float* __restrict__ wpp,
                      float* __restrict__ wta, float* __restrict__ wtp) {
    int idx = blockIdx.x*256 + threadIdx.x;   // 64*162 = 10368
    if (idx < 64*162) {
        int c = idx / 162;
        int r = idx - c*162;       // oc*9 + pos
        int oc = r / 9, pos = r - oc*9;
        size_t s = ((size_t)oc*CC + c)*9 + pos;
        wta[idx] = wpa[s];
        wtp[idx] = wpp[s];
    }
}

// ------------- K3: offset conv 3x3, all 18 oc per block, both planes ----------
__global__ __launch_bounds__(256) void k_off2(const float* __restrict__ amp,
                                              const float* __restrict__ pha,
                                              const float* __restrict__ wptA,
                                              const float* __restrict__ wptP,
                                              const float* __restrict__ bpA,
                                              const float* __restrict__ bpP,
                                              float* __restrict__ offa,
                                              float* __restrict__ offp) {
    __shared__ float colb[2][3][260];
    int tid = threadIdx.x;
    int bid = blockIdx.x;
    int sel = (bid >= BB*WF) ? 1 : 0;
    int rb = sel ? bid - BB*WF : bid;
    int j = rb % WF;
    int b = rb / WF;
    const float* img = sel ? pha : amp;
    const float* wpt = sel ? wptP : wptA;
    const float* bp  = sel ? bpP  : bpA;
    float* off = sel ? offp : offa;

    const float* ib = img + (size_t)b*CC*NPIX + (size_t)j*HH;
    bool jm = (j > 0), jp = (j < WF-1);

    float acc[18];
    #pragma unroll
    for (int o = 0; o < 18; ++o) acc[o] = bp[o];

    if (tid < 12) {
        int bufi = tid & 1;
        int dj = (tid >> 1) % 3;
        int e = tid / 6;
        colb[bufi][dj][e ? 257 : 0] = 0.f;
    }
    {
        const float* cb = ib;
        colb[0][1][tid+1] = cb[tid];
        colb[0][0][tid+1] = jm ? cb[tid - HH] : 0.f;
        colb[0][2][tid+1] = jp ? cb[tid + HH] : 0.f;
    }
    __syncthreads();

    for (int c = 0; c < CC; ++c) {
        int cur = c & 1;
        if (c + 1 < CC) {
            const float* cb = ib + (size_t)(c+1)*NPIX;
            colb[cur^1][1][tid+1] = cb[tid];
            colb[cur^1][0][tid+1] = jm ? cb[tid - HH] : 0.f;
            colb[cur^1][2][tid+1] = jp ? cb[tid + HH] : 0.f;
        }
        float v[9];
        #pragma unroll
        for (int di = 0; di < 3; ++di)
            #pragma unroll
            for (int dj = 0; dj < 3; ++dj)
                v[di*3+dj] = colb[cur][dj][tid + di];
        const float* wc = wpt + c*162;
        #pragma unroll
        for (int o = 0; o < 18; ++o) {
            #pragma unroll
            for (int p = 0; p < 9; ++p)
                acc[o] = fmaf(wc[o*9+p], v[p], acc[o]);
        }
        __syncthreads();
    }

    size_t ob = ((size_t)(b*18)*WF + j)*HH + tid;
    #pragma unroll
    for (int o = 0; o < 18; ++o)
        off[ob + (size_t)o*WF*HH] = acc[o];
}

// ------------- K4: deformable sampling + stride-3 conv via split-bf16 MFMA ----
#define SPAD 328
__global__ __launch_bounds__(256) void k_deform(const float* __restrict__ imgc,
                                                const float* __restrict__ off,
                                                const unsigned short* __restrict__ wh,
                                                const unsigned short* __restrict__ wl,
                                                float* __restrict__ out) {
    __shared__ int   cidx[4][144];
    __shared__ float cwgt[4][144];
    __shared__ __align__(16) unsigned short Sh[16][SPAD];
    __shared__ __align__(16) unsigned short Sl[16][SPAD];
    int tid = threadIdx.x;
    int bid = blockIdx.x;
    int it = bid & 15;
    int rest = bid >> 4;
    int j = rest % WF;
    int b = rest / WF;
    int i0 = it * 16;

    if (tid < 144) {
        int pix = tid / 9;
        int pos = tid % 9;
        int ki = pos / 3, kj = pos % 3;
        int i = i0 + pix;
        int r = 3*i + ki - 1;
        int s = 3*j + kj - 1;
        float g[4] = {0.f,0.f,0.f,0.f};
        int ix[4] = {-1,-1,-1,-1};
        if (r >= 0 && s >= 0) {
            int hq = r/3, nx = r%3;
            int wq = s/3, ny = s%3;
            int n = nx*3 + ny;
            float ox = off[((size_t)(b*18 + n)*WF + wq)*HH + hq];
            float oy = off[((size_t)(b*18 + 9 + n)*WF + wq)*HH + hq];
            float pxf = (float)(hq + nx) + ox;
            float pyf = (float)(wq + ny) + oy;
            float qx = floorf(pxf), qy = floorf(pyf);
            float qltx = fminf(fmaxf(qx, 0.f), 257.f);
            float qlty = fminf(fmaxf(qy, 0.f), 130.f);
            float qrbx = fminf(fmaxf(qx + 1.f, 0.f), 257.f);
            float qrby = fminf(fmaxf(qy + 1.f, 0.f), 130.f);
            float pxc = fminf(fmaxf(pxf, 0.f), 257.f);
            float pyc = fminf(fmaxf(pyf, 0.f), 130.f);
            float glt = (1.f + (qltx - pxc)) * (1.f + (qlty - pyc));
            float grb = (1.f - (qrbx - pxc)) * (1.f - (qrby - pyc));
            float glb = (1.f + (qltx - pxc)) * (1.f - (qrby - pyc));
            float grt = (1.f - (qrbx - pxc)) * (1.f + (qlty - pyc));
            int ax0 = (int)qltx, ax1 = (int)qrbx;
            int ay0 = (int)qlty, ay1 = (int)qrby;
            int cx[4] = {ax0, ax1, ax0, ax1};
            int cy[4] = {ay0, ay1, ay1, ay0};
            g[0]=glt; g[1]=grb; g[2]=glb; g[3]=grt;
            #pragma unroll
            for (int q = 0; q < 4; ++q) {
                int a = cx[q], bq = cy[q];
                ix[q] = (a >= 1 && a <= 256 && bq >= 1 && bq <= 129)
                        ? ((bq-1)*HH + (a-1))*CC : -1;
            }
        }
        #pragma unroll
        for (int q = 0; q < 4; ++q) { cidx[q][tid] = ix[q]; cwgt[q][tid] = g[q]; }
    }
    __syncthreads();

    const float* cb = imgc + (size_t)b * (size_t)WF * HH * CC;
    int lane = tid & 63;
    int w = tid >> 6;
    int l15 = lane & 15;
    int l4 = lane >> 4;
    float4v acc = {0.f, 0.f, 0.f, 0.f};
    const unsigned short* wbh = wh + (size_t)(w*16 + l15)*576 + l4*8;
    const unsigned short* wbl = wl + (size_t)(w*16 + l15)*576 + l4*8;

    // ---- chunk 0: pos 0..3 (K=256) ----
    for (int t = tid; t < 4096; t += 256) {
        int c = t & 63;
        int s = t >> 6;              // 0..63
        int pix = s >> 2, pos = s & 3;
        int combo = pix*9 + pos;
        float sum = 0.f;
        #pragma unroll
        for (int q = 0; q < 4; ++q) {
            int ofs = cidx[q][combo];
            float v = (ofs >= 0) ? cb[(size_t)ofs + c] : 0.f;
            sum += cwgt[q][combo] * v;
        }
        unsigned short h = bf16r(sum);
        Sh[pix][pos*64 + c] = h;
        Sl[pix][pos*64 + c] = bf16r(sum - bf16f(h));
    }
    __syncthreads();
    #pragma unroll
    for (int k0 = 0; k0 < 256; k0 += 32) {
        short8v Ah = *(const short8v*)&wbh[k0];
        short8v Al = *(const short8v*)&wbl[k0];
        short8v Bh = *(const short8v*)&Sh[l15][k0 + l4*8];
        short8v Bl = *(const short8v*)&Sl[l15][k0 + l4*8];
        acc = __builtin_amdgcn_mfma_f32_16x16x32_bf16(Ah, Bh, acc, 0, 0, 0);
        acc = __builtin_amdgcn_mfma_f32_16x16x32_bf16(Ah, Bl, acc, 0, 0, 0);
        acc = __builtin_amdgcn_mfma_f32_16x16x32_bf16(Al, Bh, acc, 0, 0, 0);
    }
    __syncthreads();

    // ---- chunk 1: pos 4..8 (K=320) ----
    for (int t = tid; t < 5120; t += 256) {
        int c = t & 63;
        int s = t >> 6;              // 0..79
        int pix = s / 5, pp = s - pix*5;
        int combo = pix*9 + 4 + pp;
        float sum = 0.f;
        #pragma unroll
        for (int q = 0; q < 4; ++q) {
            int ofs = cidx[q][combo];
            float v = (ofs >= 0) ? cb[(size_t)ofs + c] : 0.f;
            sum += cwgt[q][combo] * v;
        }
        unsigned short h = bf16r(sum);
        Sh[pix][pp*64 + c] = h;
        Sl[pix][pp*64 + c] = bf16r(sum - bf16f(h));
    }
    __syncthreads();
    #pragma unroll
    for (int k0 = 0; k0 < 320; k0 += 32) {
        short8v Ah = *(const short8v*)&wbh[256 + k0];
        short8v Al = *(const short8v*)&wbl[256 + k0];
        short8v Bh = *(const short8v*)&Sh[l15][k0 + l4*8];
        short8v Bl = *(const short8v*)&Sl[l15][k0 + l4*8];
        acc = __builtin_amdgcn_mfma_f32_16x16x32_bf16(Ah, Bh, acc, 0, 0, 0);
        acc = __builtin_amdgcn_mfma_f32_16x16x32_bf16(Ah, Bl, acc, 0, 0, 0);
        acc = __builtin_amdgcn_mfma_f32_16x16x32_bf16(Al, Bh, acc, 0, 0, 0);
    }

    // ---- epilogue: D[row=oc_local][col=px] ----
    size_t ob = (size_t)b*CC*NPIX + (size_t)j*HH + i0;
    #pragma unroll
    for (int r = 0; r < 4; ++r) {
        int oc = w*16 + l4*4 + r;
        out[ob + (size_t)oc*NPIX + l15] = acc[r];
    }
}

// ------------- K5: fused 1x1 convs + trig combine -------------
__global__ __launch_bounds__(256) void k_combine(const float* __restrict__ ampc,
                                                 const float* __restrict__ phac,
                                                 float* __restrict__ a3,
                                                 float* __restrict__ p3,
                                                 const float* __restrict__ w1a,
                                                 const float* __restrict__ b1a,
                                                 const float* __restrict__ w1p,
                                                 const float* __restrict__ b1p) {
    __shared__ float la[64][65], lp[64][65];
    int tid = threadIdx.x;
    int bid = blockIdx.x;
    int quarter = bid & 3;
    int rest = bid >> 2;
    int j = rest % WF;
    int b = rest / WF;
    int i0 = quarter * 64;
    size_t gbase = ((size_t)(b*WF + j)*HH + i0) * CC;
    for (int rep = 0; rep < 16; ++rep) {
        int t = rep*256 + tid;
        int pix = t >> 6;
        int c = t & 63;
        la[c][pix] = ampc[gbase + t];
        lp[c][pix] = phac[gbase + t];
    }
    __syncthreads();
    int ii = tid & 63;
    int wv = tid >> 6;
    float acc_a[16], acc_p[16];
    #pragma unroll
    for (int q = 0; q < 16; ++q) { acc_a[q] = b1a[wv*16+q]; acc_p[q] = b1p[wv*16+q]; }
    for (int c = 0; c < CC; ++c) {
        float av = la[c][ii], pv = lp[c][ii];
        #pragma unroll
        for (int q = 0; q < 16; ++q) {
            acc_a[q] += w1a[(wv*16+q)*CC + c] * av;
            acc_p[q] += w1p[(wv*16+q)*CC + c] * pv;
        }
    }
    #pragma unroll
    for (int q = 0; q < 16; ++q) {
        int oc = wv*16 + q;
        size_t idx = (size_t)(b*CC + oc)*NPIX + (size_t)j*HH + i0 + ii;
        float a3v = a3[idx];
        float p3v = p3[idx];
        float s1, c1, s3, c3;
        sincosf(acc_p[q], &s1, &c1);
        sincosf(p3v, &s3, &c3);
        float re = acc_a[q]*c3 + a3v*c1 + 3e-8f;
        float im = a3v*s1 + acc_a[q]*s3 + 2e-8f;
        a3[idx] = re;
        p3[idx] = im;
    }
}

// ------------- K6: inverse column fft (lane-contiguous r2[bc][k][t] store) ----
__global__ __launch_bounds__(256) void k_ifft_cols(const float* __restrict__ ocre,
                                                   const float* __restrict__ ocim,
                                                   const float2* __restrict__ twg,
                                                   float* __restrict__ r2re,
                                                   float* __restrict__ r2im) {
    __shared__ float2 xs[256], ys[256];
    __shared__ float2 tw[256];
    __shared__ float2 tw16[16];
    int t = threadIdx.x;
    int bid = blockIdx.x;
    int k = bid % WF;
    int bc = bid / WF;
    size_t base = ((size_t)bc*WF + k)*HH;
    tw[t] = twg[t];
    if (t < 16) tw16[t] = twg[t*16];
    xs[t] = make_float2(ocre[base + t], ocim[base + t]);
    __syncthreads();
    float2 X = fft256_lds<1>(xs, ys, tw, tw16, t);
    r2re[base + t] = X.x * (1.0f/256.0f);
    r2im[base + t] = X.y * (1.0f/256.0f);
}

// ------------- K7: hermitian row irfft + abs, 16 rows/block, LDS-tile --------
__global__ __launch_bounds__(256) void k_irfft_rows(const float* __restrict__ r2re,
                                                    const float* __restrict__ r2im,
                                                    const float2* __restrict__ twg,
                                                    float* __restrict__ xr) {
    __shared__ float2 work[256];
    __shared__ float tileRe[16][132], tileIm[16][132];
    __shared__ float2 tw[256];
    __shared__ float2 tw16[16];
    int t = threadIdx.x;
    int bid = blockIdx.x;
    int yt = bid & 15;
    int bc = bid >> 4;
    int y0 = yt*16;
    tw[t] = twg[t];
    if (t < 16) tw16[t] = twg[t*16];
    if (t < WF) {
        size_t base = ((size_t)bc*WF + t)*HH + y0;
        #pragma unroll
        for (int g = 0; g < 4; ++g) {
            float4 vr = *(const float4*)&r2re[base + g*4];
            float4 vi = *(const float4*)&r2im[base + g*4];
            tileRe[g*4+0][t] = vr.x; tileIm[g*4+0][t] = vi.x;
            tileRe[g*4+1][t] = vr.y; tileIm[g*4+1][t] = vi.y;
            tileRe[g*4+2][t] = vr.z; tileIm[g*4+2][t] = vi.z;
            tileRe[g*4+3][t] = vr.w; tileIm[g*4+3][t] = vi.w;
        }
    }
    __syncthreads();
    float* xb = xr + (size_t)bc*HH*WW + (size_t)y0*WW;
    int src = (t < WF) ? t : 256 - t;
    float sg = (t < WF) ? 1.f : -1.f;
    for (int r = 0; r < 16; ++r) {
        work[t] = make_float2(tileRe[r][src], sg*tileIm[r][src]);
        __syncthreads();
        float2 X = fft256_ip<1>(work, tw, tw16, t);
        xb[r*WW + t] = fabsf(X.x * (1.0f/256.0f));
        __syncthreads();                 // all lanes done with work before refill
    }
}

// ------------- K_split: xr[b][c][y][x] fp32 -> xh/xl [b][ch][y][x][32c] bf16 ---
__global__ __launch_bounds__(256) void k_split(const float* __restrict__ xr,
                                               unsigned short* __restrict__ xh,
                                               unsigned short* __restrict__ xl) {
    __shared__ float tile[64][65];
    int tid = threadIdx.x;
    int bid = blockIdx.x;
    int q = bid & 3;
    int y = (bid >> 2) & 255;
    int b = bid >> 10;
    int x0 = q*64;
    int lane = tid & 63;
    int cg = tid >> 6;
    for (int rep = 0; rep < 16; ++rep) {
        int c = cg*16 + rep;
        tile[c][lane] = xr[(((size_t)(b*CC + c)*HH + y)*WW) + x0 + lane];
    }
    __syncthreads();
    int x = tid >> 2;
    int c0 = (tid & 3)*8;
    #pragma unroll
    for (int ch = 0; ch < 2; ++ch) {
        short8v hv, lv;
        #pragma unroll
        for (int j = 0; j < 8; ++j) {
            float v = tile[ch*32 + c0 + j][x];
            unsigned short h = bf16r(v);
            float l = v - bf16f(h);
            hv[j] = (short)h;
            lv[j] = (short)bf16r(l);
        }
        size_t ob = ((((size_t)(b*2 + ch)*HH + y)*WW) + x0 + x)*32 + c0;
        *(short8v*)&xh[ob] = hv;
        *(short8v*)&xl[ob] = lv;
    }
}

// ------------- async global->LDS helper (16B/lane) -------------
__device__ __forceinline__ void gload16(const void* g, void* l) {
    __builtin_amdgcn_global_load_lds((const __attribute__((address_space(1))) void*)g,
                                     (__attribute__((address_space(3))) void*)l,
                                     16, 0, 0);
}

// ------------- K8: final 5x5 conv via split-bf16 32x32x16 MFMA ---------------
// T3 2-phase + 2-TAP-DEEP A/B register pipeline (192 cyc cover >= L2 latency;
// R10's 1-deep 96 cyc covered neither L2 ~200 nor LDS ~120 -> MfmaUtil 28%).
// T5 setprio around the per-tap MFMA cluster (2 unsynced blocks/CU).
#define CLX 68
#define CPART 544            // 8 rows * 68 px, in 16B entries
#define CPLANE 1088          // 2 parts
#define CBUF (2*CPLANE)      // one phase buffer: 2 planes, in 16B entries

__global__ __launch_bounds__(256, 2) void k_conv5m(const unsigned short* __restrict__ xh,
                                                   const unsigned short* __restrict__ xl,
                                                   const unsigned short* __restrict__ whT,
                                                   const unsigned short* __restrict__ wlT,
                                                   const float* __restrict__ b0,
                                                   const float* __restrict__ zpage,
                                                   float* __restrict__ out) {
    __shared__ __align__(16) unsigned short smem[2*CBUF*8];   // 69632 B (2 buffers)
    int tid = threadIdx.x;
    int bid0 = blockIdx.x;
    int bid = (bid0 & 7)*128 + (bid0 >> 3);   // XCD swizzle (1024 % 8 == 0)
    int q = bid & 3;
    int yb = (bid >> 2) & 63;
    int b = bid >> 8;
    int x0 = q*64;
    int y0 = yb*4;
    int lane = tid & 63;
    int w = tid >> 6;          // wave = output row within block
    int l31 = lane & 31;
    int l1  = lane >> 5;
    const unsigned short* zp = (const unsigned short*)zpage;

    // ---- staging slot descriptors (1088 items = 4x256 + 64 tail) ----
    int goffb[5];
    bool ok[5], has[5];
    int ldsu[5];
    #pragma unroll
    for (int s = 0; s < 5; ++s) {
        int item = (s < 4) ? (s*256 + tid) : (1024 + tid);
        bool h = (s < 4) || (tid < 64);          // uniform per wave
        int part = (item >= CPART) ? 1 : 0;
        int rest = item - part*CPART;
        int row = rest / CLX;
        int xi = rest - row*CLX;
        int gy = y0 + row - 2;
        int gx = x0 + xi - 2;
        bool o = h && gy >= 0 && gy < HH && gx >= 0 && gx < WW;
        has[s] = h; ok[s] = o;
        goffb[s] = o ? ((gy*WW + gx)*32 + part*8) : 0;
        ldsu[s] = ((s < 4) ? (s*256 + w*64) : (1024 + w*64)) * 8;   // wave-uniform
    }

    // bias-initialized accumulators acc[octile][pxtile]
    float16v acc[2][2];
    #pragma unroll
    for (int o2 = 0; o2 < 2; ++o2) {
        float16v bi;
        #pragma unroll
        for (int r = 0; r < 16; ++r)
            bi[r] = b0[o2*32 + (r & 3) + 8*(r >> 2) + 4*l1];
        acc[o2][0] = bi;
        acc[o2][1] = bi;
    }

#define STAGE(P, BUF) do { \
        size_t chb = ((size_t)(b*2 + ((P) >> 1)) << 16) * 32; \
        int phofs = ((P) & 1) * 16; \
        unsigned short* dbase = smem + (BUF)*CBUF*8; \
        _Pragma("unroll") \
        for (int s = 0; s < 5; ++s) { \
            if (has[s]) { \
                const unsigned short* sh_ = ok[s] ? &xh[chb + goffb[s] + phofs] : zp; \
                const unsigned short* sl_ = ok[s] ? &xl[chb + goffb[s] + phofs] : zp; \
                gload16(sh_, dbase + ldsu[s]); \
                gload16(sl_, dbase + CPLANE*8 + ldsu[s]); \
            } \
        } \
    } while (0)

#define LOADA(TAP, P, A) do { \
        size_t wb = ((size_t)((TAP)*64 + l31))*64 + (P)*16 + l1*8; \
        A[0] = *(const short8v*)&whT[wb]; \
        A[1] = *(const short8v*)&whT[wb + 2048]; \
        A[2] = *(const short8v*)&wlT[wb]; \
        A[3] = *(const short8v*)&wlT[wb + 2048]; \
    } while (0)

#define LOADB(TAP, BUF, Bv) do { \
        int dy_ = (TAP) / 5, dx_ = (TAP) - dy_*5; \
        int a0 = (BUF)*CBUF*8 + (l1*CPART + (w + dy_)*CLX + l31 + dx_)*8; \
        Bv[0] = *(const short8v*)&smem[a0]; \
        Bv[1] = *(const short8v*)&smem[a0 + 256]; \
        Bv[2] = *(const short8v*)&smem[CPLANE*8 + a0]; \
        Bv[3] = *(const short8v*)&smem[CPLANE*8 + a0 + 256]; \
    } while (0)

#define MFMAS(A, Bv) do { \
        __builtin_amdgcn_s_setprio(1); \
        acc[0][0] = __builtin_amdgcn_mfma_f32_32x32x16_bf16(A[0], Bv[0], acc[0][0], 0,0,0); \
        acc[0][1] = __builtin_amdgcn_mfma_f32_32x32x16_bf16(A[0], Bv[1], acc[0][1], 0,0,0); \
        acc[1][0] = __builtin_amdgcn_mfma_f32_32x32x16_bf16(A[1], Bv[0], acc[1][0], 0,0,0); \
        acc[1][1] = __builtin_amdgcn_mfma_f32_32x32x16_bf16(A[1], Bv[1], acc[1][1], 0,0,0); \
        acc[0][0] = __builtin_amdgcn_mfma_f32_32x32x16_bf16(A[0], Bv[2], acc[0][0], 0,0,0); \
        acc[0][1] = __builtin_amdgcn_mfma_f32_32x32x16_bf16(A[0], Bv[3], acc[0][1], 0,0,0); \
        acc[1][0] = __builtin_amdgcn_mfma_f32_32x32x16_bf16(A[1], Bv[2], acc[1][0], 0,0,0); \
        acc[1][1] = __builtin_amdgcn_mfma_f32_32x32x16_bf16(A[1], Bv[3], acc[1][1], 0,0,0); \
        acc[0][0] = __builtin_amdgcn_mfma_f32_32x32x16_bf16(A[2], Bv[0], acc[0][0], 0,0,0); \
        acc[0][1] = __builtin_amdgcn_mfma_f32_32x32x16_bf16(A[2], Bv[1], acc[0][1], 0,0,0); \
        acc[1][0] = __builtin_amdgcn_mfma_f32_32x32x16_bf16(A[3], Bv[0], acc[1][0], 0,0,0); \
        acc[1][1] = __builtin_amdgcn_mfma_f32_32x32x16_bf16(A[3], Bv[1], acc[1][1], 0,0,0); \
        __builtin_amdgcn_s_setprio(0); \
    } while (0)

#define ROT4(D, S) do { D[0]=S[0]; D[1]=S[1]; D[2]=S[2]; D[3]=S[3]; } while (0)

#define COMPUTE(P, BUF) do { \
        short8v A0_[4], A1_[4], A2_[4], B0_[4], B1_[4], B2_[4]; \
        LOADA(0, P, A0_); LOADB(0, BUF, B0_); \
        LOADA(1, P, A1_); LOADB(1, BUF, B1_); \
        _Pragma("unroll 5") \
        for (int tap = 0; tap < 25; ++tap) { \
            if (tap < 23) { LOADA(tap+2, P, A2_); LOADB(tap+2, BUF, B2_); } \
            MFMAS(A0_, B0_); \
            ROT4(A0_, A1_); ROT4(B0_, B1_); \
            if (tap < 23) { ROT4(A1_, A2_); ROT4(B1_, B2_); } \
        } \
    } while (0)

    STAGE(0, 0);
    __syncthreads();            // drains vmcnt -> buf0 ready
    STAGE(1, 1);                // in flight during COMPUTE(0)
    COMPUTE(0, 0);
    __syncthreads();            // buf1 ready; all waves done with buf0
    STAGE(2, 0);
    COMPUTE(1, 1);
    __syncthreads();
    STAGE(3, 1);
    COMPUTE(2, 0);
    __syncthreads();
    COMPUTE(3, 1);

#undef STAGE
#undef LOADA
#undef LOADB
#undef MFMAS
#undef ROT4
#undef COMPUTE

    // ---- epilogue: D col = px = l31, row = oc_local = (r&3)+8*(r>>2)+4*l1 ----
    int y = y0 + w;
    #pragma unroll
    for (int o2 = 0; o2 < 2; ++o2) {
        #pragma unroll
        for (int p2 = 0; p2 < 2; ++p2) {
            #pragma unroll
            for (int r = 0; r < 16; ++r) {
                int oc = o2*32 + (r & 3) + 8*(r >> 2) + 4*l1;
                int x = x0 + p2*32 + l31;
                out[(((size_t)(b*CC + oc)*HH + y)*WW) + x] = acc[o2][p2][r];
            }
        }
    }
}

extern "C" void kernel_launch(void* const* d_in, const int* in_sizes, int n_in,
                              void* d_out, int out_size, void* d_ws, size_t ws_size,
                              hipStream_t stream) {
    const float* x    = (const float*)d_in[0];
    const float* wp_a = (const float*)d_in[1];
    const float* bp_a = (const float*)d_in[2];
    const float* wc_a = (const float*)d_in[3];
    const float* w1_a = (const float*)d_in[4];
    const float* b1_a = (const float*)d_in[5];
    const float* wp_p = (const float*)d_in[6];
    const float* bp_p = (const float*)d_in[7];
    const float* wc_p = (const float*)d_in[8];
    const float* w1_p = (const float*)d_in[9];
    const float* b1_p = (const float*)d_in[10];
    const float* w0   = (const float*)d_in[11];
    const float* b0   = (const float*)d_in[12];
    float* out = (float*)d_out;
    float* ws  = (float*)d_ws;

    float* R0 = ws;
    float* R1 = ws + 2*NS;
    float* R2 = ws + 4*NS;

    float* r1re = R0;
    float* r1im = R0 + NS;
    float* amp  = R1;
    float* pha  = R1 + NS;
    float* ampc = R0;
    float* phac = R0 + NS;
    size_t offsz = (size_t)BB*18*NPIX;
    float* offa = R2;
    float* offp = R2 + offsz;
    unsigned short* wsp = (unsigned short*)(R2 + 2*offsz);
    unsigned short* whA = wsp;
    unsigned short* wlA = wsp + 36864;
    unsigned short* whP = wsp + 2*36864;
    unsigned short* wlP = wsp + 3*36864;
    unsigned short* whT = wsp + 4*36864;
    unsigned short* wlT = whT + 25*64*64;
    float* wptA = (float*)(wlT + 25*64*64);
    float* wptP = wptA + 64*162;
    float2* twg = (float2*)(wptP + 64*162);
    float* zpage = (float*)(twg + 256);    // 256 floats of zeros (1 KB)
    float* A3   = R1;
    float* P3   = R1 + NS;
    float* r2re = R0;
    float* r2im = R0 + NS;
    float* xrp  = R1;
    unsigned short* xhp = (unsigned short*)R0;
    unsigned short* xlp = xhp + (size_t)BB*2*HH*WW*32;

    k_tw<<<1, 256, 0, stream>>>(twg, zpage);
    k_wct<<<144, 256, 0, stream>>>(wc_a, whA, wlA);
    k_wct<<<144, 256, 0, stream>>>(wc_p, whP, wlP);
    k_wsplit<<<400, 256, 0, stream>>>(w0, whT, wlT);
    k_wpt<<<41, 256, 0, stream>>>(wp_a, wp_p, wptA, wptP);
    k_fft_rows<<<BB*CC*16, 256, 0, stream>>>(x, twg, r1re, r1im);
    k_fft_cols<<<BB*CC*WF, 256, 0, stream>>>(r1re, r1im, twg, amp, pha);
    k_pack<<<BB*WF*4, 256, 0, stream>>>(amp, ampc);
    k_pack<<<BB*WF*4, 256, 0, stream>>>(pha, phac);
    k_off2<<<2*BB*WF, 256, 0, stream>>>(amp, pha, wptA, wptP, bp_a, bp_p, offa, offp);
    k_deform<<<BB*WF*16, 256, 0, stream>>>(ampc, offa, whA, wlA, A3);
    k_deform<<<BB*WF*16, 256, 0, stream>>>(phac, offp, whP, wlP, P3);
    k_combine<<<BB*WF*4, 256, 0, stream>>>(ampc, phac, A3, P3, w1_a, b1_a, w1_p, b1_p);
    k_ifft_cols<<<BB*CC*WF, 256, 0, stream>>>(A3, P3, twg, r2re, r2im);
    k_irfft_rows<<<BB*CC*16, 256, 0, stream>>>(r2re, r2im, twg, xrp);
    k_split<<<BB*HH*4, 256, 0, stream>>>(xrp, xhp, xlp);
    k_conv5m<<<BB*64*4, 256, 0, stream>>>(xhp, xlp, whT, wlT, b0, zpage, out);
}

// Round 13
// 1350.827 us; speedup vs baseline: 1.0768x; 1.0768x over previous
//
#include <hip/hip_runtime.h>
#include <math.h>

#define BB 4
#define CC 64
#define HH 256
#define WW 256
#define WF 129
#define NPIX (WF*HH)                 // 33024
#define NS ((size_t)BB*CC*NPIX)      // 8454144 floats per plane-set
#define TWOPI 6.283185307179586f

typedef __attribute__((ext_vector_type(8))) short short8v;
typedef __attribute__((ext_vector_type(4))) float float4v;
typedef __attribute__((ext_vector_type(16))) float float16v;

// ---------------- four-step 256-point complex FFT in LDS ----------------
__device__ __forceinline__ float2 cmulf(float2 a, float2 b) {
    return make_float2(a.x*b.x - a.y*b.y, a.x*b.y + a.y*b.x);
}

template<int SIGN>
__device__ __forceinline__ float2 fft256_lds(const float2* __restrict__ xs,
                                             float2* __restrict__ ys,
                                             const float2* __restrict__ tw,
                                             const float2* __restrict__ tw16,
                                             int t) {
    int k1 = t & 15, n2 = t >> 4;
    float2 acc = make_float2(0.f, 0.f);
    #pragma unroll
    for (int n1 = 0; n1 < 16; ++n1) {
        float2 v = xs[n1*16 + n2];
        float2 w = tw16[(n1*k1) & 15];
        float ws = (SIGN < 0) ? -w.y : w.y;
        acc.x = fmaf(v.x, w.x, fmaf(-v.y, ws, acc.x));
        acc.y = fmaf(v.x, ws, fmaf( v.y, w.x, acc.y));
    }
    float2 w2 = tw[n2*k1];
    float w2s = (SIGN < 0) ? -w2.y : w2.y;
    ys[t] = cmulf(acc, make_float2(w2.x, w2s));
    __syncthreads();
    float2 acc2 = make_float2(0.f, 0.f);
    #pragma unroll
    for (int m2 = 0; m2 < 16; ++m2) {
        float2 v = ys[m2*16 + k1];
        float2 w = tw16[(m2*n2) & 15];
        float ws = (SIGN < 0) ? -w.y : w.y;
        acc2.x = fmaf(v.x, w.x, fmaf(-v.y, ws, acc2.x));
        acc2.y = fmaf(v.x, ws, fmaf( v.y, w.x, acc2.y));
    }
    return acc2;
}

// In-place variant (single buffer, two internal barriers) — identical arithmetic.
template<int SIGN>
__device__ __forceinline__ float2 fft256_ip(float2* __restrict__ buf,
                                            const float2* __restrict__ tw,
                                            const float2* __restrict__ tw16,
                                            int t) {
    int k1 = t & 15, n2 = t >> 4;
    float2 acc = make_float2(0.f, 0.f);
    #pragma unroll
    for (int n1 = 0; n1 < 16; ++n1) {
        float2 v = buf[n1*16 + n2];
        float2 w = tw16[(n1*k1) & 15];
        float ws = (SIGN < 0) ? -w.y : w.y;
        acc.x = fmaf(v.x, w.x, fmaf(-v.y, ws, acc.x));
        acc.y = fmaf(v.x, ws, fmaf( v.y, w.x, acc.y));
    }
    float2 w2 = tw[n2*k1];
    float w2s = (SIGN < 0) ? -w2.y : w2.y;
    float2 mid = cmulf(acc, make_float2(w2.x, w2s));
    __syncthreads();
    buf[t] = mid;
    __syncthreads();
    float2 acc2 = make_float2(0.f, 0.f);
    #pragma unroll
    for (int m2 = 0; m2 < 16; ++m2) {
        float2 v = buf[m2*16 + k1];
        float2 w = tw16[(m2*n2) & 15];
        float ws = (SIGN < 0) ? -w.y : w.y;
        acc2.x = fmaf(v.x, w.x, fmaf(-v.y, ws, acc2.x));
        acc2.y = fmaf(v.x, ws, fmaf( v.y, w.x, acc2.y));
    }
    return acc2;
}

// ------------- K_tw: fill twiddle table + zero page -------------
__global__ void k_tw(float2* __restrict__ twg, float* __restrict__ zp) {
    int m = threadIdx.x;
    float s, c;
    sincosf((TWOPI/256.f) * (float)m, &s, &c);
    twg[m] = make_float2(c, s);
    zp[m] = 0.f;
}

// ---------------- K1: row rfft, 16 rows/block, PAIRED real FFTs -------------
// Two real rows per complex FFT (z = a + i*b): 8 FFTs instead of 16.
// Unpack X_a = (Z[k]+conj(Z[N-k]))/2, X_b = (Z[k]-conj(Z[N-k]))/(2i) via a
// mirror LDS read (stride -1: conflict-free). Mathematically exact.
__global__ __launch_bounds__(256) void k_fft_rows(const float* __restrict__ x,
                                                  const float2* __restrict__ twg,
                                                  float* __restrict__ r1re,
                                                  float* __restrict__ r1im) {
    __shared__ float2 work[256];
    __shared__ float tileRe[16][132], tileIm[16][132];
    __shared__ float2 tw[256];
    __shared__ float2 tw16[16];
    int t = threadIdx.x;
    int bid = blockIdx.x;
    int yt = bid & 15;
    int bc = bid >> 4;
    int y0 = yt*16;
    tw[t] = twg[t];
    if (t < 16) tw16[t] = twg[t*16];
    const float* xb = x + (size_t)bc*HH*WW + (size_t)y0*WW;
    for (int p = 0; p < 8; ++p) {
        __syncthreads();                 // work reusable; tw visible at p=0
        work[t] = make_float2(xb[(2*p)*WW + t], xb[(2*p+1)*WW + t]);
        __syncthreads();
        float2 Z = fft256_ip<-1>(work, tw, tw16, t);
        __syncthreads();                 // all lanes done reading work's mid vals
        work[t] = Z;
        __syncthreads();
        if (t < WF) {
            float2 Zk = work[t];
            float2 Zm = work[(256 - t) & 255];
            tileRe[2*p][t]   = 0.5f*(Zk.x + Zm.x);
            tileIm[2*p][t]   = 0.5f*(Zk.y - Zm.y);
            tileRe[2*p+1][t] = 0.5f*(Zk.y + Zm.y);
            tileIm[2*p+1][t] = 0.5f*(Zm.x - Zk.x);
        }
    }
    __syncthreads();
    if (t < WF) {
        size_t base = ((size_t)bc*WF + t)*HH + y0;
        #pragma unroll
        for (int g = 0; g < 4; ++g) {
            float4 vr = make_float4(tileRe[g*4][t], tileRe[g*4+1][t],
                                    tileRe[g*4+2][t], tileRe[g*4+3][t]);
            float4 vi = make_float4(tileIm[g*4][t], tileIm[g*4+1][t],
                                    tileIm[g*4+2][t], tileIm[g*4+3][t]);
            *(float4*)&r1re[base + g*4] = vr;
            *(float4*)&r1im[base + g*4] = vi;
        }
    }
}

// ------------- K2: column fft + amp/pha -------------
__global__ __launch_bounds__(256) void k_fft_cols(const float* __restrict__ r1re,
                                                  const float* __restrict__ r1im,
                                                  const float2* __restrict__ twg,
                                                  float* __restrict__ amp,
                                                  float* __restrict__ pha) {
    __shared__ float2 xs[256], ys[256];
    __shared__ float2 tw[256];
    __shared__ float2 tw16[16];
    int t = threadIdx.x;
    int bid = blockIdx.x;
    int k = bid % WF;
    int bc = bid / WF;
    size_t base = ((size_t)bc*WF + k)*HH;
    tw[t] = twg[t];
    if (t < 16) tw16[t] = twg[t*16];
    xs[t] = make_float2(r1re[base + t], r1im[base + t]);
    __syncthreads();
    float2 X = fft256_lds<-1>(xs, ys, tw, tw16, t);
    amp[base + t] = sqrtf(X.x*X.x + X.y*X.y);
    pha[base + t] = atan2f(X.y, X.x);
}

// ------------- K_pack: [b,c,k,m] -> channel-innermost [b,k,m,c] -------------
__global__ __launch_bounds__(256) void k_pack(const float* __restrict__ src,
                                              float* __restrict__ dst) {
    __shared__ float tile[64][65];
    int tid = threadIdx.x;
    int bid = blockIdx.x;
    int it = bid & 3;
    int rest = bid >> 2;
    int k = rest % WF;
    int b = rest / WF;
    int i0 = it*64;
    int ii = tid & 63;
    int cg = tid >> 6;
    for (int rep = 0; rep < 16; ++rep) {
        int c = cg*16 + rep;
        tile[c][ii] = src[(size_t)(b*CC + c)*NPIX + (size_t)k*HH + i0 + ii];
    }
    __syncthreads();
    for (int rep = 0; rep < 16; ++rep) {
        int m = cg*16 + rep;
        dst[((size_t)(b*WF + k)*HH + i0 + m)*CC + ii] = tile[ii][m];
    }
}

// ------------- bf16 helpers -------------
__device__ __forceinline__ unsigned short bf16r(float f) {
    unsigned u = __float_as_uint(f);
    unsigned r = (u + 0x7FFFu + ((u >> 16) & 1u)) >> 16;
    return (unsigned short)r;
}
__device__ __forceinline__ float bf16f(unsigned short h) {
    return __uint_as_float(((unsigned)h) << 16);
}

// ------------- K_wct: wc[oc][c][3][3] -> split bf16 [oc][pos*64+c] -------------
__global__ void k_wct(const float* __restrict__ wc,
                      unsigned short* __restrict__ wh,
                      unsigned short* __restrict__ wl) {
    int idx = blockIdx.x*256 + threadIdx.x;   // 64*576 = 36864
    if (idx < 64*576) {
        int k = idx % 576;
        int oc = idx / 576;
        int pos = k >> 6;
        int c = k & 63;
        float v = wc[((size_t)oc*64 + c)*9 + pos];
        unsigned short h = bf16r(v);
        wh[idx] = h;
        wl[idx] = bf16r(v - bf16f(h));
    }
}

// ------------- K_wsplit: w0[oc][c][5][5] -> whT/wlT [tap][oc][c] bf16 split ----
__global__ void k_wsplit(const float* __restrict__ w0,
                         unsigned short* __restrict__ whT,
                         unsigned short* __restrict__ wlT) {
    int idx = blockIdx.x*256 + threadIdx.x;   // 25*64*64 = 102400
    if (idx < 25*64*64) {
        int c = idx & 63;
        int t = idx >> 6;
        int oc = t & 63;
        int tap = t >> 6;
        float v = w0[((size_t)oc*CC + c)*25 + tap];
        unsigned short h = bf16r(v);
        float l = v - bf16f(h);
        whT[idx] = h;
        wlT[idx] = bf16r(l);
    }
}

// ------------- K_wpt: wp[oc][c][3][3] -> wpt[c][oc*9+pos] (both planes) -------
__global__ void k_wpt(const float* __restrict__ wpa, const float* __restrict__ wpp,
                      float* __restrict__ wta, float* __restrict__ wtp) {
    int idx = blockIdx.x*256 + threadIdx.x;   // 64*162 = 10368
    if (idx < 64*162) {
        int c = idx / 162;
        int r = idx - c*162;       // oc*9 + pos
        int oc = r / 9, pos = r - oc*9;
        size_t s = ((size_t)oc*CC + c)*9 + pos;
        wta[idx] = wpa[s];
        wtp[idx] = wpp[s];
    }
}

// ------------- K3: offset conv 3x3, all 18 oc per block, both planes ----------
__global__ __launch_bounds__(256) void k_off2(const float* __restrict__ amp,
                                              const float* __restrict__ pha,
                                              const float* __restrict__ wptA,
                                              const float* __restrict__ wptP,
                                              const float* __restrict__ bpA,
                                              const float* __restrict__ bpP,
                                              float* __restrict__ offa,
                                              float* __restrict__ offp) {
    __shared__ float colb[2][3][260];
    int tid = threadIdx.x;
    int bid = blockIdx.x;
    int sel = (bid >= BB*WF) ? 1 : 0;
    int rb = sel ? bid - BB*WF : bid;
    int j = rb % WF;
    int b = rb / WF;
    const float* img = sel ? pha : amp;
    const float* wpt = sel ? wptP : wptA;
    const float* bp  = sel ? bpP  : bpA;
    float* off = sel ? offp : offa;

    const float* ib = img + (size_t)b*CC*NPIX + (size_t)j*HH;
    bool jm = (j > 0), jp = (j < WF-1);

    float acc[18];
    #pragma unroll
    for (int o = 0; o < 18; ++o) acc[o] = bp[o];

    if (tid < 12) {
        int bufi = tid & 1;
        int dj = (tid >> 1) % 3;
        int e = tid / 6;
        colb[bufi][dj][e ? 257 : 0] = 0.f;
    }
    {
        const float* cb = ib;
        colb[0][1][tid+1] = cb[tid];
        colb[0][0][tid+1] = jm ? cb[tid - HH] : 0.f;
        colb[0][2][tid+1] = jp ? cb[tid + HH] : 0.f;
    }
    __syncthreads();

    for (int c = 0; c < CC; ++c) {
        int cur = c & 1;
        if (c + 1 < CC) {
            const float* cb = ib + (size_t)(c+1)*NPIX;
            colb[cur^1][1][tid+1] = cb[tid];
            colb[cur^1][0][tid+1] = jm ? cb[tid - HH] : 0.f;
            colb[cur^1][2][tid+1] = jp ? cb[tid + HH] : 0.f;
        }
        float v[9];
        #pragma unroll
        for (int di = 0; di < 3; ++di)
            #pragma unroll
            for (int dj = 0; dj < 3; ++dj)
                v[di*3+dj] = colb[cur][dj][tid + di];
        const float* wc = wpt + c*162;
        #pragma unroll
        for (int o = 0; o < 18; ++o) {
            #pragma unroll
            for (int p = 0; p < 9; ++p)
                acc[o] = fmaf(wc[o*9+p], v[p], acc[o]);
        }
        __syncthreads();
    }

    size_t ob = ((size_t)(b*18)*WF + j)*HH + tid;
    #pragma unroll
    for (int o = 0; o < 18; ++o)
        off[ob + (size_t)o*WF*HH] = acc[o];
}

// ------------- K4: deformable sampling + stride-3 conv via split-bf16 MFMA ----
#define SPAD 328
__global__ __launch_bounds__(256) void k_deform(const float* __restrict__ imgc,
                                                const float* __restrict__ off,
                                                const unsigned short* __restrict__ wh,
                                                const unsigned short* __restrict__ wl,
                                                float* __restrict__ out) {
    __shared__ int   cidx[4][144];
    __shared__ float cwgt[4][144];
    __shared__ __align__(16) unsigned short Sh[16][SPAD];
    __shared__ __align__(16) unsigned short Sl[16][SPAD];
    int tid = threadIdx.x;
    int bid = blockIdx.x;
    int it = bid & 15;
    int rest = bid >> 4;
    int j = rest % WF;
    int b = rest / WF;
    int i0 = it * 16;

    if (tid < 144) {
        int pix = tid / 9;
        int pos = tid % 9;
        int ki = pos / 3, kj = pos % 3;
        int i = i0 + pix;
        int r = 3*i + ki - 1;
        int s = 3*j + kj - 1;
        float g[4] = {0.f,0.f,0.f,0.f};
        int ix[4] = {-1,-1,-1,-1};
        if (r >= 0 && s >= 0) {
            int hq = r/3, nx = r%3;
            int wq = s/3, ny = s%3;
            int n = nx*3 + ny;
            float ox = off[((size_t)(b*18 + n)*WF + wq)*HH + hq];
            float oy = off[((size_t)(b*18 + 9 + n)*WF + wq)*HH + hq];
            float pxf = (float)(hq + nx) + ox;
            float pyf = (float)(wq + ny) + oy;
            float qx = floorf(pxf), qy = floorf(pyf);
            float qltx = fminf(fmaxf(qx, 0.f), 257.f);
            float qlty = fminf(fmaxf(qy, 0.f), 130.f);
            float qrbx = fminf(fmaxf(qx + 1.f, 0.f), 257.f);
            float qrby = fminf(fmaxf(qy + 1.f, 0.f), 130.f);
            float pxc = fminf(fmaxf(pxf, 0.f), 257.f);
            float pyc = fminf(fmaxf(pyf, 0.f), 130.f);
            float glt = (1.f + (qltx - pxc)) * (1.f + (qlty - pyc));
            float grb = (1.f - (qrbx - pxc)) * (1.f - (qrby - pyc));
            float glb = (1.f + (qltx - pxc)) * (1.f - (qrby - pyc));
            float grt = (1.f - (qrbx - pxc)) * (1.f + (qlty - pyc));
            int ax0 = (int)qltx, ax1 = (int)qrbx;
            int ay0 = (int)qlty, ay1 = (int)qrby;
            int cx[4] = {ax0, ax1, ax0, ax1};
            int cy[4] = {ay0, ay1, ay1, ay0};
            g[0]=glt; g[1]=grb; g[2]=glb; g[3]=grt;
            #pragma unroll
            for (int q = 0; q < 4; ++q) {
                int a = cx[q], bq = cy[q];
                ix[q] = (a >= 1 && a <= 256 && bq >= 1 && bq <= 129)
                        ? ((bq-1)*HH + (a-1))*CC : -1;
            }
        }
        #pragma unroll
        for (int q = 0; q < 4; ++q) { cidx[q][tid] = ix[q]; cwgt[q][tid] = g[q]; }
    }
    __syncthreads();

    const float* cb = imgc + (size_t)b * (size_t)WF * HH * CC;
    int lane = tid & 63;
    int w = tid >> 6;
    int l15 = lane & 15;
    int l4 = lane >> 4;
    float4v acc = {0.f, 0.f, 0.f, 0.f};
    const unsigned short* wbh = wh + (size_t)(w*16 + l15)*576 + l4*8;
    const unsigned short* wbl = wl + (size_t)(w*16 + l15)*576 + l4*8;

    // ---- chunk 0: pos 0..3 (K=256) ----
    for (int t = tid; t < 4096; t += 256) {
        int c = t & 63;
        int s = t >> 6;              // 0..63
        int pix = s >> 2, pos = s & 3;
        int combo = pix*9 + pos;
        float sum = 0.f;
        #pragma unroll
        for (int q = 0; q < 4; ++q) {
            int ofs = cidx[q][combo];
            float v = (ofs >= 0) ? cb[(size_t)ofs + c] : 0.f;
            sum += cwgt[q][combo] * v;
        }
        unsigned short h = bf16r(sum);
        Sh[pix][pos*64 + c] = h;
        Sl[pix][pos*64 + c] = bf16r(sum - bf16f(h));
    }
    __syncthreads();
    #pragma unroll
    for (int k0 = 0; k0 < 256; k0 += 32) {
        short8v Ah = *(const short8v*)&wbh[k0];
        short8v Al = *(const short8v*)&wbl[k0];
        short8v Bh = *(const short8v*)&Sh[l15][k0 + l4*8];
        short8v Bl = *(const short8v*)&Sl[l15][k0 + l4*8];
        acc = __builtin_amdgcn_mfma_f32_16x16x32_bf16(Ah, Bh, acc, 0, 0, 0);
        acc = __builtin_amdgcn_mfma_f32_16x16x32_bf16(Ah, Bl, acc, 0, 0, 0);
        acc = __builtin_amdgcn_mfma_f32_16x16x32_bf16(Al, Bh, acc, 0, 0, 0);
    }
    __syncthreads();

    // ---- chunk 1: pos 4..8 (K=320) ----
    for (int t = tid; t < 5120; t += 256) {
        int c = t & 63;
        int s = t >> 6;              // 0..79
        int pix = s / 5, pp = s - pix*5;
        int combo = pix*9 + 4 + pp;
        float sum = 0.f;
        #pragma unroll
        for (int q = 0; q < 4; ++q) {
            int ofs = cidx[q][combo];
            float v = (ofs >= 0) ? cb[(size_t)ofs + c] : 0.f;
            sum += cwgt[q][combo] * v;
        }
        unsigned short h = bf16r(sum);
        Sh[pix][pp*64 + c] = h;
        Sl[pix][pp*64 + c] = bf16r(sum - bf16f(h));
    }
    __syncthreads();
    #pragma unroll
    for (int k0 = 0; k0 < 320; k0 += 32) {
        short8v Ah = *(const short8v*)&wbh[256 + k0];
        short8v Al = *(const short8v*)&wbl[256 + k0];
        short8v Bh = *(const short8v*)&Sh[l15][k0 + l4*8];
        short8v Bl = *(const short8v*)&Sl[l15][k0 + l4*8];
        acc = __builtin_amdgcn_mfma_f32_16x16x32_bf16(Ah, Bh, acc, 0, 0, 0);
        acc = __builtin_amdgcn_mfma_f32_16x16x32_bf16(Ah, Bl, acc, 0, 0, 0);
        acc = __builtin_amdgcn_mfma_f32_16x16x32_bf16(Al, Bh, acc, 0, 0, 0);
    }

    // ---- epilogue: D[row=oc_local][col=px] ----
    size_t ob = (size_t)b*CC*NPIX + (size_t)j*HH + i0;
    #pragma unroll
    for (int r = 0; r < 4; ++r) {
        int oc = w*16 + l4*4 + r;
        out[ob + (size_t)oc*NPIX + l15] = acc[r];
    }
}

// ------------- K5: fused 1x1 convs + trig combine -------------
__global__ __launch_bounds__(256) void k_combine(const float* __restrict__ ampc,
                                                 const float* __restrict__ phac,
                                                 float* __restrict__ a3,
                                                 float* __restrict__ p3,
                                                 const float* __restrict__ w1a,
                                                 const float* __restrict__ b1a,
                                                 const float* __restrict__ w1p,
                                                 const float* __restrict__ b1p) {
    __shared__ float la[64][65], lp[64][65];
    int tid = threadIdx.x;
    int bid = blockIdx.x;
    int quarter = bid & 3;
    int rest = bid >> 2;
    int j = rest % WF;
    int b = rest / WF;
    int i0 = quarter * 64;
    size_t gbase = ((size_t)(b*WF + j)*HH + i0) * CC;
    for (int rep = 0; rep < 16; ++rep) {
        int t = rep*256 + tid;
        int pix = t >> 6;
        int c = t & 63;
        la[c][pix] = ampc[gbase + t];
        lp[c][pix] = phac[gbase + t];
    }
    __syncthreads();
    int ii = tid & 63;
    int wv = tid >> 6;
    float acc_a[16], acc_p[16];
    #pragma unroll
    for (int q = 0; q < 16; ++q) { acc_a[q] = b1a[wv*16+q]; acc_p[q] = b1p[wv*16+q]; }
    for (int c = 0; c < CC; ++c) {
        float av = la[c][ii], pv = lp[c][ii];
        #pragma unroll
        for (int q = 0; q < 16; ++q) {
            acc_a[q] += w1a[(wv*16+q)*CC + c] * av;
            acc_p[q] += w1p[(wv*16+q)*CC + c] * pv;
        }
    }
    #pragma unroll
    for (int q = 0; q < 16; ++q) {
        int oc = wv*16 + q;
        size_t idx = (size_t)(b*CC + oc)*NPIX + (size_t)j*HH + i0 + ii;
        float a3v = a3[idx];
        float p3v = p3[idx];
        float s1, c1, s3, c3;
        sincosf(acc_p[q], &s1, &c1);
        sincosf(p3v, &s3, &c3);
        float re = acc_a[q]*c3 + a3v*c1 + 3e-8f;
        float im = a3v*s1 + acc_a[q]*s3 + 2e-8f;
        a3[idx] = re;
        p3[idx] = im;
    }
}

// ------------- K6: inverse column fft (lane-contiguous r2[bc][k][t] store) ----
__global__ __launch_bounds__(256) void k_ifft_cols(const float* __restrict__ ocre,
                                                   const float* __restrict__ ocim,
                                                   const float2* __restrict__ twg,
                                                   float* __restrict__ r2re,
                                                   float* __restrict__ r2im) {
    __shared__ float2 xs[256], ys[256];
    __shared__ float2 tw[256];
    __shared__ float2 tw16[16];
    int t = threadIdx.x;
    int bid = blockIdx.x;
    int k = bid % WF;
    int bc = bid / WF;
    size_t base = ((size_t)bc*WF + k)*HH;
    tw[t] = twg[t];
    if (t < 16) tw16[t] = twg[t*16];
    xs[t] = make_float2(ocre[base + t], ocim[base + t]);
    __syncthreads();
    float2 X = fft256_lds<1>(xs, ys, tw, tw16, t);
    r2re[base + t] = X.x * (1.0f/256.0f);
    r2im[base + t] = X.y * (1.0f/256.0f);
}

// ------------- K7: hermitian row irfft + abs, PAIRED inverse FFTs ------------
// Z[k] = Xa[k] + i*Xb[k] (hermitian-extended): one inverse FFT yields both
// real rows in (re, im). 8 FFTs instead of 16.
__global__ __launch_bounds__(256) void k_irfft_rows(const float* __restrict__ r2re,
                                                    const float* __restrict__ r2im,
                                                    const float2* __restrict__ twg,
                                                    float* __restrict__ xr) {
    __shared__ float2 work[256];
    __shared__ float tileRe[16][132], tileIm[16][132];
    __shared__ float2 tw[256];
    __shared__ float2 tw16[16];
    int t = threadIdx.x;
    int bid = blockIdx.x;
    int yt = bid & 15;
    int bc = bid >> 4;
    int y0 = yt*16;
    tw[t] = twg[t];
    if (t < 16) tw16[t] = twg[t*16];
    if (t < WF) {
        size_t base = ((size_t)bc*WF + t)*HH + y0;
        #pragma unroll
        for (int g = 0; g < 4; ++g) {
            float4 vr = *(const float4*)&r2re[base + g*4];
            float4 vi = *(const float4*)&r2im[base + g*4];
            tileRe[g*4+0][t] = vr.x; tileIm[g*4+0][t] = vi.x;
            tileRe[g*4+1][t] = vr.y; tileIm[g*4+1][t] = vi.y;
            tileRe[g*4+2][t] = vr.z; tileIm[g*4+2][t] = vi.z;
            tileRe[g*4+3][t] = vr.w; tileIm[g*4+3][t] = vi.w;
        }
    }
    __syncthreads();
    float* xb = xr + (size_t)bc*HH*WW + (size_t)y0*WW;
    for (int p = 0; p < 8; ++p) {
        if (t < WF) {
            float ar = tileRe[2*p][t],   ai = tileIm[2*p][t];
            float br = tileRe[2*p+1][t], bi = tileIm[2*p+1][t];
            work[t] = make_float2(ar - bi, ai + br);
        } else {
            int m = 256 - t;
            float ar = tileRe[2*p][m],   ai = tileIm[2*p][m];
            float br = tileRe[2*p+1][m], bi = tileIm[2*p+1][m];
            work[t] = make_float2(ar + bi, br - ai);
        }
        __syncthreads();
        float2 Y = fft256_ip<1>(work, tw, tw16, t);
        xb[(2*p)*WW + t]   = fabsf(Y.x * (1.0f/256.0f));
        xb[(2*p+1)*WW + t] = fabsf(Y.y * (1.0f/256.0f));
        __syncthreads();                 // all lanes done with work before refill
    }
}

// ------------- K_split: xr[b][c][y][x] fp32 -> xh/xl [b][ch][y][x][32c] bf16 ---
__global__ __launch_bounds__(256) void k_split(const float* __restrict__ xr,
                                               unsigned short* __restrict__ xh,
                                               unsigned short* __restrict__ xl) {
    __shared__ float tile[64][65];
    int tid = threadIdx.x;
    int bid = blockIdx.x;
    int q = bid & 3;
    int y = (bid >> 2) & 255;
    int b = bid >> 10;
    int x0 = q*64;
    int lane = tid & 63;
    int cg = tid >> 6;
    for (int rep = 0; rep < 16; ++rep) {
        int c = cg*16 + rep;
        tile[c][lane] = xr[(((size_t)(b*CC + c)*HH + y)*WW) + x0 + lane];
    }
    __syncthreads();
    int x = tid >> 2;
    int c0 = (tid & 3)*8;
    #pragma unroll
    for (int ch = 0; ch < 2; ++ch) {
        short8v hv, lv;
        #pragma unroll
        for (int j = 0; j < 8; ++j) {
            float v = tile[ch*32 + c0 + j][x];
            unsigned short h = bf16r(v);
            float l = v - bf16f(h);
            hv[j] = (short)h;
            lv[j] = (short)bf16r(l);
        }
        size_t ob = ((((size_t)(b*2 + ch)*HH + y)*WW) + x0 + x)*32 + c0;
        *(short8v*)&xh[ob] = hv;
        *(short8v*)&xl[ob] = lv;
    }
}

// ------------- async global->LDS helper (16B/lane) -------------
__device__ __forceinline__ void gload16(const void* g, void* l) {
    __builtin_amdgcn_global_load_lds((const __attribute__((address_space(1))) void*)g,
                                     (__attribute__((address_space(3))) void*)l,
                                     16, 0, 0);
}

// ------------- K8: final 5x5 conv via split-bf16 32x32x16 MFMA ---------------
#define CLX 68
#define CPART 544            // 8 rows * 68 px, in 16B entries
#define CPLANE 1088          // 2 parts
#define CBUF (2*CPLANE)      // one phase buffer: 2 planes, in 16B entries

__global__ __launch_bounds__(256, 2) void k_conv5m(const unsigned short* __restrict__ xh,
                                                   const unsigned short* __restrict__ xl,
                                                   const unsigned short* __restrict__ whT,
                                                   const unsigned short* __restrict__ wlT,
                                                   const float* __restrict__ b0,
                                                   const float* __restrict__ zpage,
                                                   float* __restrict__ out) {
    __shared__ __align__(16) unsigned short smem[2*CBUF*8];   // 69632 B (2 buffers)
    int tid = threadIdx.x;
    int bid0 = blockIdx.x;
    int bid = (bid0 & 7)*128 + (bid0 >> 3);   // XCD swizzle (1024 % 8 == 0)
    int q = bid & 3;
    int yb = (bid >> 2) & 63;
    int b = bid >> 8;
    int x0 = q*64;
    int y0 = yb*4;
    int lane = tid & 63;
    int w = tid >> 6;          // wave = output row within block
    int l31 = lane & 31;
    int l1  = lane >> 5;
    const unsigned short* zp = (const unsigned short*)zpage;

    int goffb[5];
    bool ok[5], has[5];
    int ldsu[5];
    #pragma unroll
    for (int s = 0; s < 5; ++s) {
        int item = (s < 4) ? (s*256 + tid) : (1024 + tid);
        bool h = (s < 4) || (tid < 64);          // uniform per wave
        int part = (item >= CPART) ? 1 : 0;
        int rest = item - part*CPART;
        int row = rest / CLX;
        int xi = rest - row*CLX;
        int gy = y0 + row - 2;
        int gx = x0 + xi - 2;
        bool o = h && gy >= 0 && gy < HH && gx >= 0 && gx < WW;
        has[s] = h; ok[s] = o;
        goffb[s] = o ? ((gy*WW + gx)*32 + part*8) : 0;
        ldsu[s] = ((s < 4) ? (s*256 + w*64) : (1024 + w*64)) * 8;   // wave-uniform
    }

    float16v acc[2][2];
    #pragma unroll
    for (int o2 = 0; o2 < 2; ++o2) {
        float16v bi;
        #pragma unroll
        for (int r = 0; r < 16; ++r)
            bi[r] = b0[o2*32 + (r & 3) + 8*(r >> 2) + 4*l1];
        acc[o2][0] = bi;
        acc[o2][1] = bi;
    }

#define STAGE(P, BUF) do { \
        size_t chb = ((size_t)(b*2 + ((P) >> 1)) << 16) * 32; \
        int phofs = ((P) & 1) * 16; \
        unsigned short* dbase = smem + (BUF)*CBUF*8; \
        _Pragma("unroll") \
        for (int s = 0; s < 5; ++s) { \
            if (has[s]) { \
                const unsigned short* sh_ = ok[s] ? &xh[chb + goffb[s] + phofs] : zp; \
                const unsigned short* sl_ = ok[s] ? &xl[chb + goffb[s] + phofs] : zp; \
                gload16(sh_, dbase + ldsu[s]); \
                gload16(sl_, dbase + CPLANE*8 + ldsu[s]); \
            } \
        } \
    } while (0)

#define LOADA(TAP, P, A) do { \
        size_t wb = ((size_t)((TAP)*64 + l31))*64 + (P)*16 + l1*8; \
        A[0] = *(const short8v*)&whT[wb]; \
        A[1] = *(const short8v*)&whT[wb + 2048]; \
        A[2] = *(const short8v*)&wlT[wb]; \
        A[3] = *(const short8v*)&wlT[wb + 2048]; \
    } while (0)

#define LOADB(TAP, BUF, Bv) do { \
        int dy_ = (TAP) / 5, dx_ = (TAP) - dy_*5; \
        int a0 = (BUF)*CBUF*8 + (l1*CPART + (w + dy_)*CLX + l31 + dx_)*8; \
        Bv[0] = *(const short8v*)&smem[a0]; \
        Bv[1] = *(const short8v*)&smem[a0 + 256]; \
        Bv[2] = *(const short8v*)&smem[CPLANE*8 + a0]; \
        Bv[3] = *(const short8v*)&smem[CPLANE*8 + a0 + 256]; \
    } while (0)

#define MFMAS(A, Bv) do { \
        __builtin_amdgcn_s_setprio(1); \
        acc[0][0] = __builtin_amdgcn_mfma_f32_32x32x16_bf16(A[0], Bv[0], acc[0][0], 0,0,0); \
        acc[0][1] = __builtin_amdgcn_mfma_f32_32x32x16_bf16(A[0], Bv[1], acc[0][1], 0,0,0); \
        acc[1][0] = __builtin_amdgcn_mfma_f32_32x32x16_bf16(A[1], Bv[0], acc[1][0], 0,0,0); \
        acc[1][1] = __builtin_amdgcn_mfma_f32_32x32x16_bf16(A[1], Bv[1], acc[1][1], 0,0,0); \
        acc[0][0] = __builtin_amdgcn_mfma_f32_32x32x16_bf16(A[0], Bv[2], acc[0][0], 0,0,0); \
        acc[0][1] = __builtin_amdgcn_mfma_f32_32x32x16_bf16(A[0], Bv[3], acc[0][1], 0,0,0); \
        acc[1][0] = __builtin_amdgcn_mfma_f32_32x32x16_bf16(A[1], Bv[2], acc[1][0], 0,0,0); \
        acc[1][1] = __builtin_amdgcn_mfma_f32_32x32x16_bf16(A[1], Bv[3], acc[1][1], 0,0,0); \
        acc[0][0] = __builtin_amdgcn_mfma_f32_32x32x16_bf16(A[2], Bv[0], acc[0][0], 0,0,0); \
        acc[0][1] = __builtin_amdgcn_mfma_f32_32x32x16_bf16(A[2], Bv[1], acc[0][1], 0,0,0); \
        acc[1][0] = __builtin_amdgcn_mfma_f32_32x32x16_bf16(A[3], Bv[0], acc[1][0], 0,0,0); \
        acc[1][1] = __builtin_amdgcn_mfma_f32_32x32x16_bf16(A[3], Bv[1], acc[1][1], 0,0,0); \
        __builtin_amdgcn_s_setprio(0); \
    } while (0)

#define ROT4(D, S) do { D[0]=S[0]; D[1]=S[1]; D[2]=S[2]; D[3]=S[3]; } while (0)

#define COMPUTE(P, BUF) do { \
        short8v A0_[4], A1_[4], A2_[4], B0_[4], B1_[4], B2_[4]; \
        LOADA(0, P, A0_); LOADB(0, BUF, B0_); \
        LOADA(1, P, A1_); LOADB(1, BUF, B1_); \
        _Pragma("unroll 5") \
        for (int tap = 0; tap < 25; ++tap) { \
            if (tap < 23) { LOADA(tap+2, P, A2_); LOADB(tap+2, BUF, B2_); } \
            MFMAS(A0_, B0_); \
            ROT4(A0_, A1_); ROT4(B0_, B1_); \
            if (tap < 23) { ROT4(A1_, A2_); ROT4(B1_, B2_); } \
        } \
    } while (0)

    STAGE(0, 0);
    __syncthreads();
    STAGE(1, 1);
    COMPUTE(0, 0);
    __syncthreads();
    STAGE(2, 0);
    COMPUTE(1, 1);
    __syncthreads();
    STAGE(3, 1);
    COMPUTE(2, 0);
    __syncthreads();
    COMPUTE(3, 1);

#undef STAGE
#undef LOADA
#undef LOADB
#undef MFMAS
#undef ROT4
#undef COMPUTE

    int y = y0 + w;
    #pragma unroll
    for (int o2 = 0; o2 < 2; ++o2) {
        #pragma unroll
        for (int p2 = 0; p2 < 2; ++p2) {
            #pragma unroll
            for (int r = 0; r < 16; ++r) {
                int oc = o2*32 + (r & 3) + 8*(r >> 2) + 4*l1;
                int x = x0 + p2*32 + l31;
                out[(((size_t)(b*CC + oc)*HH + y)*WW) + x] = acc[o2][p2][r];
            }
        }
    }
}

extern "C" void kernel_launch(void* const* d_in, const int* in_sizes, int n_in,
                              void* d_out, int out_size, void* d_ws, size_t ws_size,
                              hipStream_t stream) {
    const float* x    = (const float*)d_in[0];
    const float* wp_a = (const float*)d_in[1];
    const float* bp_a = (const float*)d_in[2];
    const float* wc_a = (const float*)d_in[3];
    const float* w1_a = (const float*)d_in[4];
    const float* b1_a = (const float*)d_in[5];
    const float* wp_p = (const float*)d_in[6];
    const float* bp_p = (const float*)d_in[7];
    const float* wc_p = (const float*)d_in[8];
    const float* w1_p = (const float*)d_in[9];
    const float* b1_p = (const float*)d_in[10];
    const float* w0   = (const float*)d_in[11];
    const float* b0   = (const float*)d_in[12];
    float* out = (float*)d_out;
    float* ws  = (float*)d_ws;

    float* R0 = ws;
    float* R1 = ws + 2*NS;
    float* R2 = ws + 4*NS;

    float* r1re = R0;
    float* r1im = R0 + NS;
    float* amp  = R1;
    float* pha  = R1 + NS;
    float* ampc = R0;
    float* phac = R0 + NS;
    size_t offsz = (size_t)BB*18*NPIX;
    float* offa = R2;
    float* offp = R2 + offsz;
    unsigned short* wsp = (unsigned short*)(R2 + 2*offsz);
    unsigned short* whA = wsp;
    unsigned short* wlA = wsp + 36864;
    unsigned short* whP = wsp + 2*36864;
    unsigned short* wlP = wsp + 3*36864;
    unsigned short* whT = wsp + 4*36864;
    unsigned short* wlT = whT + 25*64*64;
    float* wptA = (float*)(wlT + 25*64*64);
    float* wptP = wptA + 64*162;
    float2* twg = (float2*)(wptP + 64*162);
    float* zpage = (float*)(twg + 256);    // 256 floats of zeros (1 KB)
    float* A3   = R1;
    float* P3   = R1 + NS;
    float* r2re = R0;
    float* r2im = R0 + NS;
    float* xrp  = R1;
    unsigned short* xhp = (unsigned short*)R0;
    unsigned short* xlp = xhp + (size_t)BB*2*HH*WW*32;

    k_tw<<<1, 256, 0, stream>>>(twg, zpage);
    k_wct<<<144, 256, 0, stream>>>(wc_a, whA, wlA);
    k_wct<<<144, 256, 0, stream>>>(wc_p, whP, wlP);
    k_wsplit<<<400, 256, 0, stream>>>(w0, whT, wlT);
    k_wpt<<<41, 256, 0, stream>>>(wp_a, wp_p, wptA, wptP);
    k_fft_rows<<<BB*CC*16, 256, 0, stream>>>(x, twg, r1re, r1im);
    k_fft_cols<<<BB*CC*WF, 256, 0, stream>>>(r1re, r1im, twg, amp, pha);
    k_pack<<<BB*WF*4, 256, 0, stream>>>(amp, ampc);
    k_pack<<<BB*WF*4, 256, 0, stream>>>(pha, phac);
    k_off2<<<2*BB*WF, 256, 0, stream>>>(amp, pha, wptA, wptP, bp_a, bp_p, offa, offp);
    k_deform<<<BB*WF*16, 256, 0, stream>>>(ampc, offa, whA, wlA, A3);
    k_deform<<<BB*WF*16, 256, 0, stream>>>(phac, offp, whP, wlP, P3);
    k_combine<<<BB*WF*4, 256, 0, stream>>>(ampc, phac, A3, P3, w1_a, b1_a, w1_p, b1_p);
    k_ifft_cols<<<BB*CC*WF, 256, 0, stream>>>(A3, P3, twg, r2re, r2im);
    k_irfft_rows<<<BB*CC*16, 256, 0, stream>>>(r2re, r2im, twg, xrp);
    k_split<<<BB*HH*4, 256, 0, stream>>>(xrp, xhp, xlp);
    k_conv5m<<<BB*64*4, 256, 0, stream>>>(xhp, xlp, whT, wlT, b0, zpage, out);
}